// Round 1
// 1978.189 us; speedup vs baseline: 1.5041x; 1.5041x over previous
//
#include <hip/hip_runtime.h>
#include <hip/hip_bf16.h>
#include <math.h>

typedef unsigned short u16;
typedef unsigned int u32;
typedef float f32x4 __attribute__((ext_vector_type(4)));
typedef __bf16 bf16x8 __attribute__((ext_vector_type(8)));
typedef u32 u32x4 __attribute__((ext_vector_type(4)));
typedef u16 u16x4 __attribute__((ext_vector_type(4)));

#define DEV static __device__ __forceinline__

DEV float bf2f(u16 u) { u32 x = ((u32)u) << 16; return __builtin_bit_cast(float, x); }
DEV u16 f2bf(float f) { __bf16 h = (__bf16)f; return __builtin_bit_cast(u16, h); }
DEV bf16x8 ldb8(const u16* p) { u32x4 v = *(const u32x4*)p; return __builtin_bit_cast(bf16x8, v); }

// async global->LDS, 16B per lane; LDS dest is wave-uniform base + lane*16
DEV void gload16(const u16* g, u16* l) {
    __builtin_amdgcn_global_load_lds((const __attribute__((address_space(1))) void*)g,
                                     (__attribute__((address_space(3))) void*)l, 16, 0, 0);
}

// ---------------- weight packing ----------------
__global__ void pack_simple(const float* __restrict__ lat_w, const float* __restrict__ proj_w,
                            const float* __restrict__ val_w, const float* __restrict__ off_w,
                            const float* __restrict__ attw_w, const float* __restrict__ out_w,
                            u16* __restrict__ wlat, u16* __restrict__ wproj, u16* __restrict__ wval,
                            u16* __restrict__ woffaw, u16* __restrict__ wout)
{
    int i = blockIdx.x * 256 + threadIdx.x;
    if (i < 262144) { wlat[i] = f2bf(lat_w[i]); return; }
    i -= 262144;
    if (i < 65536) { wproj[i] = f2bf(proj_w[i]); return; }
    i -= 65536;
    if (i < 4096) { wval[i] = f2bf(val_w[i]); return; }
    i -= 4096;
    if (i < 32768) { woffaw[i] = f2bf(off_w[i]); return; }
    i -= 32768;
    if (i < 16384) { woffaw[32768 + i] = f2bf(attw_w[i]); return; }
    i -= 16384;
    wout[i] = f2bf(out_w[i]);
}

// conv_w [4][256][320][3][3] -> [4][256][2880] with k = (dy*3+dx)*320 + ci
__global__ void pack_conv(const float* __restrict__ conv_w, u16* __restrict__ wconv)
{
    int i = blockIdx.x * 256 + threadIdx.x;   // < 2949120
    int l = i / 737280; int r = i % 737280;
    int o = r / 2880;   int k = r % 2880;
    int tap = k / 320;  int ci = k % 320;
    int dy = tap / 3, dx = tap % 3;
    wconv[i] = f2bf(conv_w[(((l * 256 + o) * 320 + ci) * 3 + dy) * 3 + dx]);
}

// posq[q][64], q = lvl*1024 + y*32 + x ; sine pos (positions 1..32) + level_embed
__global__ void pos_kernel(const float* __restrict__ level_embed, float* __restrict__ posq)
{
    int i = blockIdx.x * 256 + threadIdx.x;   // < 262144
    int e = i & 63; int q = i >> 6;
    int lvl = q >> 10; int hw = q & 1023;
    int y = hw >> 5, x = hw & 31;
    int e2 = e & 31;
    int j = e2 >> 1;
    float t = exp2f(13.287712379549449f * (float)j * (1.f / 16.f));   // 10000^(j/16)
    float p = (float)((e < 32 ? y : x) + 1) / t;
    float v = (e2 & 1) ? cosf(p) : sinf(p);
    posq[i] = v + level_embed[lvl * 64 + e];
}

// x[lvl] fp32 [b][c][1024] -> xT bf16 [lvl][b][p][256]
__global__ __launch_bounds__(1024) void transpose_x(const float* __restrict__ x0, const float* __restrict__ x1,
                                                    const float* __restrict__ x2, const float* __restrict__ x3,
                                                    u16* __restrict__ xT)
{
    __shared__ u16 tile[32][33];
    int zb = blockIdx.z; int lvl = zb >> 4; int b = zb & 15;
    const float* x = lvl == 0 ? x0 : lvl == 1 ? x1 : lvl == 2 ? x2 : x3;
    int c0 = blockIdx.y * 32, p0 = blockIdx.x * 32;
    int tx = threadIdx.x, ty = threadIdx.y;
    tile[ty][tx] = f2bf(x[(b * 256 + c0 + ty) * 1024 + p0 + tx]);
    __syncthreads();
    xT[((long)(lvl * 16 + b) * 1024 + p0 + ty) * 256 + c0 + tx] = tile[tx][ty];
}

// ---------------- generic MFMA GEMM, OUT[n][m] = sum_k A[m][k]*B[n][k] ----------------
enum { EPI_LAT = 0, EPI_SRC = 1, EPI_VAL = 2, EPI_OFFAW = 3, EPI_OUT = 4 };

template<int BM, int BN, int EPI>
__global__ __launch_bounds__(256) void gemm_k(
    const u16* __restrict__ A, const u16* __restrict__ Bm, const int K,
    float* __restrict__ outF, u16* __restrict__ outU, u16* __restrict__ outU2,
    const float* __restrict__ bias, const float* __restrict__ bias2,
    const float* __restrict__ bng, const float* __restrict__ bnb,
    const float* __restrict__ bnm, const float* __restrict__ bnv,
    const float* __restrict__ posq)
{
    constexpr int WN = BN / 64;
    const int tid = threadIdx.x;
    const int wave = tid >> 6, lane = tid & 63;
    const int quad = lane >> 4, lm = lane & 15;
    const int wm = wave / WN, wn = wave % WN;
    const int n0 = blockIdx.x * BN + wn * 64;
    const int m0 = blockIdx.y * BM + wm * 64;

    int lvl = 0;
    const u16* Ab = A;
    if constexpr (EPI == EPI_LAT) { lvl = n0 >> 14; Ab = A + lvl * 65536; }
    if constexpr (EPI == EPI_SRC) { lvl = (n0 & 4095) >> 10; Ab = A + lvl * 16384; }

    int nidx[4];
    long brow[4];
#pragma unroll
    for (int j = 0; j < 4; j++) {
        int n = n0 + j * 16 + lm;
        nidx[j] = n;
        int row = n;
        if constexpr (EPI == EPI_SRC) {
            int b = n >> 12, p = n & 1023;
            row = ((lvl * 16 + b) << 10) + p;   // latT is [lvl][b][p]
        }
        brow[j] = (long)row * K;
    }
    long arow[4];
#pragma unroll
    for (int i = 0; i < 4; i++) arow[i] = (long)(m0 + i * 16 + lm) * K;

    f32x4 acc[4][4] = {};
    for (int kb = 0; kb < K; kb += 32) {
        const int ko = kb + quad * 8;
        bf16x8 av[4], bv[4];
#pragma unroll
        for (int i = 0; i < 4; i++) av[i] = ldb8(Ab + arow[i] + ko);
#pragma unroll
        for (int j = 0; j < 4; j++) bv[j] = ldb8(Bm + brow[j] + ko);
#pragma unroll
        for (int i = 0; i < 4; i++)
#pragma unroll
            for (int j = 0; j < 4; j++)
                acc[i][j] = __builtin_amdgcn_mfma_f32_16x16x32_bf16(av[i], bv[j], acc[i][j], 0, 0, 0);
    }

#pragma unroll
    for (int i = 0; i < 4; i++) {
        const int mB = m0 + i * 16 + quad * 4;
#pragma unroll
        for (int j = 0; j < 4; j++) {
            const int n = nidx[j];
            if constexpr (EPI == EPI_LAT) {
                u16x4 w;
#pragma unroll
                for (int r = 0; r < 4; r++) w[r] = f2bf(acc[i][j][r] + bias[lvl * 256 + mB + r]);
                *(u16x4*)(outU + (long)n * 256 + mB) = w;
            } else if constexpr (EPI == EPI_SRC) {
                u16x4 w, w2;
#pragma unroll
                for (int r = 0; r < 4; r++) {
                    int m = mB + r, im = lvl * 64 + m;
                    float t = acc[i][j][r] + bias[im];
                    float sc = bng[im] * rsqrtf(bnv[im] + 1e-5f);
                    t = (t - bnm[im]) * sc + bnb[im];
                    t = fmaxf(t, 0.f);
                    w[r] = f2bf(t);
                    w2[r] = f2bf(t + posq[(n & 4095) * 64 + m]);
                }
                *(u16x4*)(outU + (long)n * 64 + mB) = w;
                *(u16x4*)(outU2 + (long)n * 64 + mB) = w2;
            } else if constexpr (EPI == EPI_VAL) {
                f32x4 o;
#pragma unroll
                for (int r = 0; r < 4; r++) o[r] = acc[i][j][r] + bias[mB + r];
                *(f32x4*)(outF + (long)n * 64 + mB) = o;
            } else if constexpr (EPI == EPI_OFFAW) {
                u16x4 w;
#pragma unroll
                for (int r = 0; r < 4; r++) {
                    int m = mB + r;
                    float bb = (m < 512) ? bias[m] : bias2[m - 512];
                    w[r] = f2bf(acc[i][j][r] + bb);
                }
                *(u16x4*)(outU + (long)n * 768 + mB) = w;
            } else {
                u16x4 w;
#pragma unroll
                for (int r = 0; r < 4; r++) w[r] = f2bf(acc[i][j][r] + bias[mB + r]);
                *(u16x4*)(outU + (long)n * 64 + mB) = w;
            }
        }
    }
}

// ---------------- deformable attention sampling ----------------
// one wave per (b,q); lane = head*8 + dh
__global__ __launch_bounds__(256) void sampler_k(
    const u16* __restrict__ offaw, const float* __restrict__ valT, u16* __restrict__ attnT)
{
    const int wave = threadIdx.x >> 6, lane = threadIdx.x & 63;
    const long bq = (long)blockIdx.x * 4 + wave;   // < 65536
    const int h = lane >> 3, d = lane & 7;
    const int q = (int)(bq & 4095);
    const int hw = q & 1023;
    const float refx = ((hw & 31) + 0.5f) * (1.f / 32.f);
    const float refy = ((hw >> 5) + 0.5f) * (1.f / 32.f);
    const u16* oa = offaw + bq * 768;
    const int lg0 = 512 + h * 32;

    float mx = -1e30f;
    for (int s = 0; s < 32; s++) mx = fmaxf(mx, bf2f(oa[lg0 + s]));
    float sum = 0.f;
    for (int s = 0; s < 32; s++) sum += expf(bf2f(oa[lg0 + s]) - mx);
    const float inv = 1.f / sum;

    const int b = (int)(bq >> 12);
    float acc = 0.f;
    for (int s = 0; s < 32; s++) {
        const int lvl = s >> 3, pt = s & 7;
        const float w = expf(bf2f(oa[lg0 + s]) - mx) * inv;
        const float offx = bf2f(oa[h * 64 + lvl * 16 + pt * 2]);
        const float offy = bf2f(oa[h * 64 + lvl * 16 + pt * 2 + 1]);
        const float gx = (refx + offx * (1.f / 32.f)) * 32.f - 0.5f;
        const float gy = (refy + offy * (1.f / 32.f)) * 32.f - 0.5f;
        const float x0f = floorf(gx), y0f = floorf(gy);
        const int x0 = (int)x0f, y0 = (int)y0f;
        const float wx = gx - x0f, wy = gy - y0f;
        const float* vb = valT + ((long)b * 4096 + lvl * 1024) * 64 + h * 8 + d;
        float v00 = 0.f, v10 = 0.f, v01 = 0.f, v11 = 0.f;
        if ((unsigned)x0 < 32u && (unsigned)y0 < 32u)             v00 = vb[(y0 * 32 + x0) * 64];
        if ((unsigned)(x0 + 1) < 32u && (unsigned)y0 < 32u)       v10 = vb[(y0 * 32 + x0 + 1) * 64];
        if ((unsigned)x0 < 32u && (unsigned)(y0 + 1) < 32u)       v01 = vb[((y0 + 1) * 32 + x0) * 64];
        if ((unsigned)(x0 + 1) < 32u && (unsigned)(y0 + 1) < 32u) v11 = vb[((y0 + 1) * 32 + x0 + 1) * 64];
        const float bi = v00 * (1.f - wx) * (1.f - wy) + v10 * wx * (1.f - wy)
                       + v01 * (1.f - wx) * wy + v11 * wx * wy;
        acc += w * bi;
    }
    attnT[bq * 64 + lane] = f2bf(acc);
}

// ---------------- build padded channel-last conv input ----------------
// nf[b][oy+1][ox+1][ci], ci<256: resized lateral; ci>=256: resized feat(src2)
__global__ void build_nf(const u16* __restrict__ latT_l, const u16* __restrict__ src2T,
                         u16* __restrict__ nf, const int lvl, const int OH, const int OW)
{
    long idx = (long)blockIdx.x * 256 + threadIdx.x;
    int ci = (int)(idx % 320); long t = idx / 320;
    int owsh = (OW == 16) ? 4 : (OW == 32) ? 5 : (OW == 64) ? 6 : 7;
    int ox = (int)(t & (OW - 1)); t >>= owsh;
    int oy = (int)(t & (OH - 1)); int b = (int)(t >> owsh);
    float sy = fmaxf((oy + 0.5f) * (32.f / (float)OH) - 0.5f, 0.f);
    float sx = fmaxf((ox + 0.5f) * (32.f / (float)OW) - 0.5f, 0.f);
    int y0 = (int)sy, x0 = (int)sx;
    float wy = sy - (float)y0, wx = sx - (float)x0;
    int y1 = min(y0 + 1, 31), x1 = min(x0 + 1, 31);
    const bool isLat = ci < 256;
    auto fetch = [&](int yy, int xx) -> float {
        int p = yy * 32 + xx;
        u16 u = isLat ? latT_l[((long)b * 1024 + p) * 256 + ci]
                      : src2T[((long)b * 4096 + lvl * 1024 + p) * 64 + (ci - 256)];
        return bf2f(u);
    };
    float v = fetch(y0, x0) * (1.f - wy) * (1.f - wx) + fetch(y0, x1) * (1.f - wy) * wx
            + fetch(y1, x0) * wy * (1.f - wx) + fetch(y1, x1) * wy * wx;
    nf[(((long)b * (OH + 2) + oy + 1) * (OW + 2) + ox + 1) * 320 + ci] = f2bf(v);
}

// ---------------- 3x3 conv as implicit GEMM (M=256 out-ch, K=2880, N=pixels) ----------------
// m97-style structure: 128x128 tile, BK=32, double-buffered LDS staged via
// global_load_lds(16B), ds_read_b128 fragments with XOR k-slot swizzle,
// one barrier per K-step. 1-D grid with bijective XCD swizzle so the two
// m-blocks of a pixel tile share an XCD's L2.
__global__ __launch_bounds__(256) void conv3x3_k(
    const u16* __restrict__ W, const u16* __restrict__ nf,
    const float* __restrict__ bias, float* __restrict__ out,
    const int OH, const int OW)
{
    __shared__ u16 Ab[2][4096];   // [buf][128 rows][32 k]
    __shared__ u16 Bb[2][4096];

    const int tid = threadIdx.x;
    const int wave = tid >> 6, lane = tid & 63;
    const int quad = lane >> 4, lm = lane & 15;
    const int wm = wave >> 1, wn = wave & 1;

    // bijective XCD swizzle (nwg % 8 == 0 for all levels): chunk per XCD,
    // consecutive lid pairs (the 2 m-blocks of one pixel tile) co-located.
    const int cpx = gridDim.x >> 3;
    const int lid = (blockIdx.x & 7) * cpx + (blockIdx.x >> 3);
    const int mblk = lid & 1, ntile = lid >> 1;
    const int m0b = mblk << 7;
    const int n0b = ntile << 7;

    const int PW = OW + 2;
    const int hw = OH * OW;
    const int hwsh = __builtin_ctz(hw), owsh = __builtin_ctz(OW);

    // ---- per-thread staging source addresses (pre-swizzled k-slot) ----
    // LDS is written linearly (lane*16B); the global source carries the
    // involutive swizzle slot' = slot ^ ((row>>1)&3); reads apply the same.
    const int swz = (((tid & 3) ^ ((tid >> 3) & 3)) << 3);   // element offset in row
    const int r0 = tid >> 2;                                  // tile row, chunk 0
    const long aSrc0 = (long)(m0b + r0) * 2880 + swz;
    const long aSrc1 = (long)(m0b + 64 + r0) * 2880 + swz;
    long bSrc0, bSrc1;
    {
        int n = n0b + r0;
        int b = n >> hwsh, rr = n & (hw - 1);
        bSrc0 = ((long)(b * (OH + 2) + (rr >> owsh)) * PW + (rr & (OW - 1))) * 320 + swz;
        n += 64;
        b = n >> hwsh; rr = n & (hw - 1);
        bSrc1 = ((long)(b * (OH + 2) + (rr >> owsh)) * PW + (rr & (OW - 1))) * 320 + swz;
    }
    const int wbase = (tid & 192) << 3;   // wave-uniform LDS element base (wave*512)

    // ---- LDS fragment read offsets (elements), swizzled ----
    const int sA = quad ^ ((lm >> 1) & 3);
    int aoff[4], boff[4];
#pragma unroll
    for (int i = 0; i < 4; i++) {
        aoff[i] = ((wm * 64 + i * 16 + lm) << 5) + (sA << 3);
        boff[i] = ((wn * 64 + i * 16 + lm) << 5) + (sA << 3);
    }

    // epilogue pixel decode
    int bj[4], oyj[4], oxj[4];
#pragma unroll
    for (int j = 0; j < 4; j++) {
        int n = n0b + wn * 64 + j * 16 + lm;
        int b = n >> hwsh, r = n & (hw - 1);
        bj[j] = b; oyj[j] = r >> owsh; oxj[j] = r & (OW - 1);
    }

    auto stage = [&](int sb, long ao, long bo) {
        gload16(W + aSrc0 + ao, &Ab[sb][wbase]);
        gload16(W + aSrc1 + ao, &Ab[sb][2048 + wbase]);
        gload16(nf + bSrc0 + bo, &Bb[sb][wbase]);
        gload16(nf + bSrc1 + bo, &Bb[sb][2048 + wbase]);
    };

    f32x4 acc[4][4] = {};
    stage(0, 0, 0);
    __syncthreads();

    int buf = 0, tap = 0, kc = 0;
    for (int step = 0; step < 90; ++step) {
        int ntap = tap, nkc = kc + 32;
        if (nkc == 320) { nkc = 0; ++ntap; }
        if (step < 89) {
            const int t3 = (ntap * 11) >> 5;                    // ntap/3 for ntap<=8
            const long bo = (long)(t3 * PW + (ntap - t3 * 3)) * 320 + nkc;
            stage(buf ^ 1, (long)ntap * 320 + nkc, bo);
        }
        bf16x8 av[4], bv[4];
#pragma unroll
        for (int i = 0; i < 4; i++) av[i] = *(const bf16x8*)&Ab[buf][aoff[i]];
#pragma unroll
        for (int j = 0; j < 4; j++) bv[j] = *(const bf16x8*)&Bb[buf][boff[j]];
#pragma unroll
        for (int i = 0; i < 4; i++)
#pragma unroll
            for (int j = 0; j < 4; j++)
                acc[i][j] = __builtin_amdgcn_mfma_f32_16x16x32_bf16(av[i], bv[j], acc[i][j], 0, 0, 0);
        __syncthreads();
        buf ^= 1; tap = ntap; kc = nkc;
    }

#pragma unroll
    for (int i = 0; i < 4; i++) {
        const int oB = m0b + wm * 64 + i * 16 + quad * 4;
#pragma unroll
        for (int j = 0; j < 4; j++) {
#pragma unroll
            for (int r = 0; r < 4; r++) {
                int o = oB + r;
                out[((long)(bj[j] * 256 + o) * OH + oyj[j]) * OW + oxj[j]] = acc[i][j][r] + bias[o];
            }
        }
    }
}

extern "C" void kernel_launch(void* const* d_in, const int* in_sizes, int n_in,
                              void* d_out, int out_size, void* d_ws, size_t ws_size,
                              hipStream_t stream)
{
    (void)in_sizes; (void)n_in; (void)out_size;
    const float* x0 = (const float*)d_in[0];
    const float* x1 = (const float*)d_in[1];
    const float* x2 = (const float*)d_in[2];
    const float* x3 = (const float*)d_in[3];
    const float* lat_w = (const float*)d_in[4];
    const float* lat_b = (const float*)d_in[5];
    const float* proj_w = (const float*)d_in[6];
    const float* proj_b = (const float*)d_in[7];
    const float* bn_g = (const float*)d_in[8];
    const float* bn_b = (const float*)d_in[9];
    const float* bn_m = (const float*)d_in[10];
    const float* bn_v = (const float*)d_in[11];
    const float* conv_w = (const float*)d_in[12];
    const float* conv_b = (const float*)d_in[13];
    const float* level_embed = (const float*)d_in[14];
    const float* off_w = (const float*)d_in[15];
    const float* off_b = (const float*)d_in[16];
    const float* attw_w = (const float*)d_in[17];
    const float* attw_b = (const float*)d_in[18];
    const float* val_w = (const float*)d_in[19];
    const float* val_b = (const float*)d_in[20];
    const float* out_w = (const float*)d_in[21];
    const float* out_b = (const float*)d_in[22];
    float* outp = (float*)d_out;
    char* ws = (char*)d_ws;

    size_t off = 0;
    auto alloc = [&](size_t bytes) { off = (off + 255) & ~(size_t)255; size_t o = off; off += bytes; return o; };
    const size_t o_wlat  = alloc(262144ull * 2);
    const size_t o_wproj = alloc(65536ull * 2);
    const size_t o_wval  = alloc(4096ull * 2);
    const size_t o_woffaw= alloc(49152ull * 2);
    const size_t o_wout  = alloc(4096ull * 2);
    const size_t o_wconv = alloc(2949120ull * 2);
    const size_t o_xT    = alloc(16777216ull * 2);
    const size_t o_latT  = alloc(16777216ull * 2);
    const size_t o_posq  = alloc(262144ull * 4);
    const size_t o_srcT  = alloc(4194304ull * 2);
    const size_t o_qT    = alloc(4194304ull * 2);
    const size_t o_valT  = alloc(4194304ull * 4);
    const size_t o_offaw = alloc(50331648ull * 2);
    const size_t o_attnT = alloc(4194304ull * 2);
    const size_t o_src2T = alloc(4194304ull * 2);
    const size_t o_nf0   = alloc(16ull * 18 * 18 * 320 * 2);
    const size_t o_nf1   = alloc(16ull * 34 * 34 * 320 * 2);
    const size_t o_nf2   = alloc(16ull * 66 * 66 * 320 * 2);
    const size_t o_nf3   = alloc(16ull * 130 * 130 * 320 * 2);
    const size_t total_needed = off;
    if (ws_size < total_needed) return;   // loud failure (output stays zero) rather than corruption

    u16* wlat  = (u16*)(ws + o_wlat);
    u16* wproj = (u16*)(ws + o_wproj);
    u16* wval  = (u16*)(ws + o_wval);
    u16* woffaw= (u16*)(ws + o_woffaw);
    u16* wout  = (u16*)(ws + o_wout);
    u16* wconv = (u16*)(ws + o_wconv);
    u16* xT    = (u16*)(ws + o_xT);
    u16* latT  = (u16*)(ws + o_latT);
    float* posq= (float*)(ws + o_posq);
    u16* srcT  = (u16*)(ws + o_srcT);
    u16* qT    = (u16*)(ws + o_qT);
    float* valT= (float*)(ws + o_valT);
    u16* offaw = (u16*)(ws + o_offaw);
    u16* attnT = (u16*)(ws + o_attnT);
    u16* src2T = (u16*)(ws + o_src2T);
    u16* nfp[4] = {(u16*)(ws + o_nf0), (u16*)(ws + o_nf1), (u16*)(ws + o_nf2), (u16*)(ws + o_nf3)};

    // zero padded conv inputs (halo must be 0 every call; ws is re-poisoned)
    hipMemsetAsync(ws + o_nf0, 0, total_needed - o_nf0, stream);

    pack_simple<<<1504, 256, 0, stream>>>(lat_w, proj_w, val_w, off_w, attw_w, out_w,
                                          wlat, wproj, wval, woffaw, wout);
    pack_conv<<<11520, 256, 0, stream>>>(conv_w, wconv);
    pos_kernel<<<1024, 256, 0, stream>>>(level_embed, posq);
    transpose_x<<<dim3(32, 8, 64), dim3(32, 32), 0, stream>>>(x0, x1, x2, x3, xT);

    // laterals: latT[lvl][b][p][256]
    gemm_k<128, 128, EPI_LAT><<<dim3(512, 2), 256, 0, stream>>>(
        wlat, xT, 256, nullptr, latT, nullptr, lat_b, nullptr, nullptr, nullptr, nullptr, nullptr, nullptr);
    // proj + BN + ReLU -> srcT, and qT = srcT + pos
    gemm_k<64, 256, EPI_SRC><<<dim3(256, 1), 256, 0, stream>>>(
        wproj, latT, 256, nullptr, srcT, qT, proj_b, nullptr, bn_g, bn_b, bn_m, bn_v, posq);
    // value
    gemm_k<64, 256, EPI_VAL><<<dim3(256, 1), 256, 0, stream>>>(
        wval, srcT, 64, valT, nullptr, nullptr, val_b, nullptr, nullptr, nullptr, nullptr, nullptr, nullptr);
    // offsets (512) + attention-weight logits (256)
    gemm_k<128, 128, EPI_OFFAW><<<dim3(512, 6), 256, 0, stream>>>(
        woffaw, qT, 64, nullptr, offaw, nullptr, off_b, attw_b, nullptr, nullptr, nullptr, nullptr, nullptr);
    // deformable sampling
    sampler_k<<<16384, 256, 0, stream>>>(offaw, valT, attnT);
    // output projection
    gemm_k<64, 256, EPI_OUT><<<dim3(256, 1), 256, 0, stream>>>(
        wout, attnT, 64, nullptr, src2T, nullptr, out_b, nullptr, nullptr, nullptr, nullptr, nullptr, nullptr);

    const int OHs[4] = {16, 32, 64, 128};
    const size_t outoff[4] = {0, 1048576, 5242880, 22020096};
    for (int l = 0; l < 4; l++) {
        int OH = OHs[l];
        long total = 16L * OH * OH * 320;
        build_nf<<<(int)(total / 256), 256, 0, stream>>>(latT + (long)l * 4194304, src2T, nfp[l], l, OH, OH);
    }
    for (int l = 0; l < 4; l++) {
        int OH = OHs[l];
        int nwg = 2 * (16 * OH * OH / 128);   // %8==0 for all levels
        conv3x3_k<<<dim3(nwg), 256, 0, stream>>>(
            wconv + (long)l * 737280, nfp[l], conv_b + l * 256, outp + outoff[l], OH, OH);
    }
}